// Round 6
// baseline (1119.765 us; speedup 1.0000x reference)
//
#include <hip/hip_runtime.h>
#include <math.h>
#include <stdint.h>

#define NSPH 7
#define NRAD 6
#define BLK  256
#define EPB  6      // edges per edge_k block (6*42 = 252 threads)
#define NE_PAD 48   // padded row: 192 B, 16B-aligned float4 loads

typedef float f32x2 __attribute__((ext_vector_type(2)));
typedef float f32x4 __attribute__((ext_vector_type(4)));

// ===== glibc sinf/cosf bit-exact replication =====
// (glibc sysdeps/ieee754/flt-32/{s_sinf.c,s_cosf.c,sincosf.h,sincosf_data.c},
//  baseline x86-64 build: f64 internals, NO fma) — verified PASS in round 3.
#define SC_HPI_INV 0x1.45F306DC9C883p+23   /* 2/pi * 2^24 */
#define SC_HPI     0x1.921FB54442D18p+0
#define SC_C0      (0x1p+0)
#define SC_C1      (-0x1.ffffffd0c621cp-2)
#define SC_C2      (0x1.55553e1068f19p-5)
#define SC_C3      (-0x1.6c087e89a359dp-10)
#define SC_C4      (0x1.99343027bf8c3p-16)
#define SC_S1      (-0x1.555545995a603p-3)
#define SC_S2      (0x1.1107605230bc4p-7)
#define SC_S3      (-0x1.994eb3774cf24p-13)

__device__ __forceinline__ unsigned abstop12(float x) {
    return (__float_as_uint(x) >> 20) & 0x7ffu;
}

__device__ __forceinline__ float sp_sin(double x, double x2) {
    double x3 = __dmul_rn(x, x2);
    double s1 = __dadd_rn(SC_S2, __dmul_rn(x2, SC_S3));
    double x7 = __dmul_rn(x3, x2);
    double s  = __dadd_rn(x, __dmul_rn(x3, SC_S1));
    return (float)__dadd_rn(s, __dmul_rn(x7, s1));
}

__device__ __forceinline__ float sp_cos(double x2, bool neg) {
    double c0 = neg ? -SC_C0 : SC_C0;
    double c1 = neg ? -SC_C1 : SC_C1;
    double c2 = neg ? -SC_C2 : SC_C2;
    double c3 = neg ? -SC_C3 : SC_C3;
    double c4 = neg ? -SC_C4 : SC_C4;
    double x4  = __dmul_rn(x2, x2);
    double c2v = __dadd_rn(c3, __dmul_rn(x2, c4));
    double c1v = __dadd_rn(c0, __dmul_rn(x2, c1));
    double x6  = __dmul_rn(x4, x2);
    double c   = __dadd_rn(c1v, __dmul_rn(x4, c2));
    return (float)__dadd_rn(c, __dmul_rn(x6, c2v));
}

__device__ __forceinline__ double reduce_fast(double x, int* np) {
    double r = __dmul_rn(x, SC_HPI_INV);
    int n = (((int)r) + 0x800000) >> 24;
    *np = n;
    return __dsub_rn(x, __dmul_rn((double)n, SC_HPI));
}

__device__ __forceinline__ float glibc_sinf(float y) {
    unsigned at = abstop12(y);
    double x = (double)y;
    if (at < 0x3f4u) {                       // |y| < 0.78125
        if (at < 0x398u) return y;           // |y| < 0x1p-12
        return sp_sin(x, __dmul_rn(x, x));
    }
    int n;
    double r = reduce_fast(x, &n);
    double s = ((n + 1) & 2) ? -1.0 : 1.0;
    bool neg = (n & 2) != 0;
    double xs = __dmul_rn(r, s);
    double x2 = __dmul_rn(r, r);
    if ((n & 1) == 0) return sp_sin(xs, x2);
    return sp_cos(x2, neg);
}

__device__ __forceinline__ float glibc_cosf(float y) {
    unsigned at = abstop12(y);
    double x = (double)y;
    if (at < 0x3f4u) {
        if (at < 0x398u) return 1.0f;
        return sp_cos(__dmul_rn(x, x), false);
    }
    int n;
    double r = reduce_fast(x, &n);
    double s = ((n + 2) & 2) ? -1.0 : 1.0;
    bool neg = ((n + 1) & 2) != 0;
    int m = n ^ 1;
    double xs = __dmul_rn(r, s);
    double x2 = __dmul_rn(r, r);
    if ((m & 1) == 0) return sp_sin(xs, x2);
    return sp_cos(x2, neg);
}

// ===== f64 spherical bessel (for zeros/bnorm; replicates _sph_jn_np) =====
__device__ __forceinline__ double jn_f64(double x, int n) {
    double s = sin(x), c = cos(x);
    double j0 = s / x;
    if (n == 0) return j0;
    double j1 = s / (x * x) - c / x;
    double jm1 = j0, j = j1;
    for (int l = 1; l < n; ++l) {
        double t = (double)(2 * l + 1) / x * j - jm1;
        jm1 = j; j = t;
    }
    return j;
}

// cst layout (floats): [0..41] zf, [42..83] bnorm, [84..90] ynorm
__global__ __launch_bounds__(704) void setup_k(float* __restrict__ cst) {
    __shared__ double pts[13];
    __shared__ double roots[12];
    __shared__ double Z[NSPH][NRAD];
    const double PI = 3.141592653589793238462643383279502884;
    int tid = threadIdx.x, wv = tid >> 6, ln = tid & 63;
    if (tid < 12) pts[tid] = PI * (double)(tid + 1);
    __syncthreads();
    if (tid < NRAD) Z[0][tid] = pts[tid];
    for (int i = 1; i < NSPH; ++i) {
        int m = NRAD + NSPH - 1 - i;  // 12 - i
        if (wv < m) {
            double a = pts[wv], b = pts[wv + 1];
            for (int r = 0; r < 9; ++r) {
                double st = (b - a) * (1.0 / 63.0);
                double f = jn_f64(a + st * (double)ln, i);
                double f0 = __shfl(f, 0);
                unsigned long long bm = __ballot((ln > 0) && (f0 * f <= 0.0));
                int idx = bm ? (__ffsll((unsigned long long)bm) - 1) : 63;
                b = a + st * (double)idx;
                a = a + st * (double)(idx - 1);
            }
            if (ln == 0) roots[wv] = 0.5 * (a + b);
        }
        __syncthreads();
        if (tid < m) pts[tid] = roots[tid];
        if (tid < NRAD) Z[i][tid] = roots[tid];
        __syncthreads();
    }
    if (tid < NSPH * NRAD) {
        int l = tid / NRAD;
        double z = Z[l][tid % NRAD];
        cst[tid] = (float)z;
        double jp = jn_f64(z, l + 1);
        cst[42 + tid] = (float)(1.0 / sqrt(0.5 * (jp * jp)));
    }
    if (tid < NSPH) {
        cst[84 + tid] = (float)sqrt((double)(2 * tid + 1) / (4.0 * PI));
    }
}

// ===== Phase A: per-(edge, l, n) rbf_env table, bit-exact chain =====
// 252 threads = 6 edges x 42 (l,n) chains; env/d shared per edge via LDS.
__global__ __launch_bounds__(252) void edge_k(
    const float* __restrict__ D, const float* __restrict__ cst,
    float* __restrict__ tab, int nE)
{
    __shared__ float zf[42], bn[42];
    __shared__ float sh_d[EPB], sh_unc[EPB];
    int tid = threadIdx.x;
    if (tid < 42) { zf[tid] = cst[tid]; bn[tid] = cst[42 + tid]; }
    int le = tid / 42;
    int k  = tid - le * 42;
    long long e = (long long)blockIdx.x * EPB + le;
    bool ok = e < (long long)nE;
    if (ok && k == 0) {
        float d = __fmul_rn(D[e], 0.2f);
        float invd = __fdiv_rn(1.0f, d);
        float d2 = d * d, d4 = d2 * d2, d5 = d4 * d, d6 = d5 * d, d7 = d6 * d;
        float env = ((invd + (-28.0f) * d5) + 48.0f * d6) + (-21.0f) * d7;
        float u_d = (d < 1.0f) ? env : 0.0f;
        const float NC = (float)0.0894427190999916;  // 0.2**1.5
        sh_unc[le] = __fmul_rn(u_d, NC);
        sh_d[le] = d;
    }
    __syncthreads();
    if (!ok) return;
    float d = sh_d[le], unc = sh_unc[le];
    int l = k / 6;

    float x = __fmul_rn(d, zf[k]);
    float s = glibc_sinf(x);
    float j = __fdiv_rn(s, x);
    if (l > 0) {
        float c = glibc_cosf(x);
        float x2 = __fmul_rn(x, x);
        float j1 = __fsub_rn(__fdiv_rn(s, x2), __fdiv_rn(c, x));
        float jm1 = j, jc = j1;
        for (int kk = 1; kk < l; ++kk) {
            float fk = __fdiv_rn((float)(2 * kk + 1), x);
            float jn2 = __fsub_rn(__fmul_rn(fk, jc), jm1);
            jm1 = jc; jc = jn2;
        }
        j = jc;
    }
    tab[e * NE_PAD + k] = __fmul_rn(unc, __fmul_rn(bn[k], j));
}

// ===== Phase B: gather + sph multiply, register-only, NT stores =====
__global__ __launch_bounds__(BLK) void trip_k(
    const float* __restrict__ Ang, const int* __restrict__ id3,
    const float* __restrict__ tab, const float* __restrict__ cst,
    float* __restrict__ out, int nT)
{
    int t = blockIdx.x * BLK + threadIdx.x;
    if (t >= nT) return;
    int e = __builtin_nontemporal_load(id3 + t);
    float ang = __builtin_nontemporal_load(Ang + t);

    // issue the 42-float gather first (latency hides under cosf/Legendre)
    const f32x4* rowv = (const f32x4*)(tab + (long long)e * NE_PAD);
    float row[42];
#pragma unroll
    for (int w = 0; w < 10; ++w) {
        f32x4 v = rowv[w];
        row[w * 4 + 0] = v.x; row[w * 4 + 1] = v.y;
        row[w * 4 + 2] = v.z; row[w * 4 + 3] = v.w;
    }
    {
        f32x2 v = ((const f32x2*)rowv)[20];
        row[40] = v.x; row[41] = v.y;
    }

    // identical numerics to round-3/4 (bit-exact output)
    float ct = glibc_cosf(ang);
    float P[NSPH];
    P[0] = 1.0f; P[1] = ct;
#pragma unroll
    for (int l = 1; l < NSPH - 1; ++l) {
        float t1 = __fmul_rn(__fmul_rn((float)(2 * l + 1), ct), P[l]);
        float t2 = __fmul_rn((float)l, P[l - 1]);
        P[l + 1] = __fdiv_rn(__fsub_rn(t1, t2), (float)(l + 1));
    }
    float yP[NSPH];
#pragma unroll
    for (int l = 0; l < NSPH; ++l) yP[l] = __fmul_rn(cst[84 + l], P[l]);

    // 21 x f32x2 nontemporal stores (rows are 8B-aligned: 168B pitch)
    f32x2* drow = (f32x2*)(out + (long long)t * 42);
#pragma unroll
    for (int p = 0; p < 21; ++p) {
        int l = (2 * p) / 6;
        f32x2 a;
        a.x = __fmul_rn(row[2 * p + 0], yP[l]);
        a.y = __fmul_rn(row[2 * p + 1], yP[l]);
        __builtin_nontemporal_store(a, drow + p);
    }
}

// ===== fallback: round-3 fused kernel (used only if ws too small) =====
__global__ __launch_bounds__(BLK) void sph_main(
    const float* __restrict__ D, const float* __restrict__ Ang,
    const int* __restrict__ id3, const float* __restrict__ cst,
    float* __restrict__ out, int nT)
{
    __shared__ float zf[42], bn[42], yn[7];
    __shared__ float stg[BLK * 42];
    int tid = threadIdx.x;
    if (tid < 42) { zf[tid] = cst[tid]; bn[tid] = cst[42 + tid]; }
    if (tid < 7)  { yn[tid] = cst[84 + tid]; }
    __syncthreads();
    int base = blockIdx.x * BLK;
    int t = base + tid;
    bool ok = t < nT;
    int e = ok ? id3[t] : 0;
    float Dv = D[e];
    float ang = ok ? Ang[t] : 0.0f;
    float d = __fmul_rn(Dv, 0.2f);
    float invd = __fdiv_rn(1.0f, d);
    float d2 = d * d, d4 = d2 * d2, d5 = d4 * d, d6 = d5 * d, d7 = d6 * d;
    float env = ((invd + (-28.0f) * d5) + 48.0f * d6) + (-21.0f) * d7;
    float u_d = (d < 1.0f) ? env : 0.0f;
    const float NC = (float)0.0894427190999916;
    float unc = __fmul_rn(u_d, NC);
    float ct = glibc_cosf(ang);
    float P[NSPH];
    P[0] = 1.0f; P[1] = ct;
#pragma unroll
    for (int l = 1; l < NSPH - 1; ++l) {
        float t1 = __fmul_rn(__fmul_rn((float)(2 * l + 1), ct), P[l]);
        float t2 = __fmul_rn((float)l, P[l - 1]);
        P[l + 1] = __fdiv_rn(__fsub_rn(t1, t2), (float)(l + 1));
    }
    float* row = &stg[tid * 42];
#pragma unroll
    for (int l = 0; l < NSPH; ++l) {
        float yPl = __fmul_rn(yn[l], P[l]);
        for (int n = 0; n < NRAD; ++n) {
            float z = zf[l * 6 + n];
            float x = __fmul_rn(d, z);
            float s = glibc_sinf(x);
            float j = __fdiv_rn(s, x);
            if (l > 0) {
                float c = glibc_cosf(x);
                float x2 = __fmul_rn(x, x);
                float j1 = __fsub_rn(__fdiv_rn(s, x2), __fdiv_rn(c, x));
                float jm1 = j, jc = j1;
                for (int kk = 1; kk < l; ++kk) {
                    float fk = __fdiv_rn((float)(2 * kk + 1), x);
                    float jn2 = __fsub_rn(__fmul_rn(fk, jc), jm1);
                    jm1 = jc; jc = jn2;
                }
                j = jc;
            }
            float re = __fmul_rn(unc, __fmul_rn(bn[l * 6 + n], j));
            row[l * 6 + n] = __fmul_rn(re, yPl);
        }
    }
    __syncthreads();
    int nv = nT - base; if (nv > BLK) nv = BLK;
    int nf2 = nv * 21;
    const float2* src = (const float2*)stg;
    float2* dst = (float2*)(out + (long long)base * 42);
    for (int i = tid; i < nf2; i += BLK) dst[i] = src[i];
}

extern "C" void kernel_launch(void* const* d_in, const int* in_sizes, int n_in,
                              void* d_out, int out_size, void* d_ws, size_t ws_size,
                              hipStream_t stream) {
    const float* D   = (const float*)d_in[0];
    const float* Ang = (const float*)d_in[1];
    const int*   id3 = (const int*)d_in[2];
    float* out = (float*)d_out;
    int nE = in_sizes[0];
    int nT = in_sizes[1];

    size_t tab_bytes = (size_t)nE * NE_PAD * sizeof(float);
    if (ws_size >= tab_bytes + 512) {
        float* tab = (float*)d_ws;
        float* cst = (float*)((char*)d_ws + tab_bytes);
        setup_k<<<1, 704, 0, stream>>>(cst);
        int gA = (nE + EPB - 1) / EPB;
        edge_k<<<gA, 252, 0, stream>>>(D, cst, tab, nE);
        int gB = (nT + BLK - 1) / BLK;
        trip_k<<<gB, BLK, 0, stream>>>(Ang, id3, tab, cst, out, nT);
    } else {
        float* cst = (float*)d_ws;   // 91 floats
        setup_k<<<1, 704, 0, stream>>>(cst);
        int grid = (nT + BLK - 1) / BLK;
        sph_main<<<grid, BLK, 0, stream>>>(D, Ang, id3, cst, out, nT);
    }
}

// Round 7
// 300.860 us; speedup vs baseline: 3.7219x; 3.7219x over previous
//
#include <hip/hip_runtime.h>
#include <math.h>
#include <stdint.h>

#define NSPH 7
#define NRAD 6
#define BLK  256
#define CHUNK 128   // trip_k LDS staging chunk (rows)
#define EPB  6      // edges per edge_k block (6*42 = 252 threads)
#define NE_PAD 48   // padded table row: 192 B, 16B-aligned float4 loads

typedef float f32x2 __attribute__((ext_vector_type(2)));
typedef float f32x4 __attribute__((ext_vector_type(4)));

// ===== glibc sinf/cosf bit-exact replication =====
// (glibc sysdeps/ieee754/flt-32/{s_sinf.c,s_cosf.c,sincosf.h,sincosf_data.c},
//  baseline x86-64 build: f64 internals, NO fma) — verified PASS rounds 3-6.
#define SC_HPI_INV 0x1.45F306DC9C883p+23   /* 2/pi * 2^24 */
#define SC_HPI     0x1.921FB54442D18p+0
#define SC_C0      (0x1p+0)
#define SC_C1      (-0x1.ffffffd0c621cp-2)
#define SC_C2      (0x1.55553e1068f19p-5)
#define SC_C3      (-0x1.6c087e89a359dp-10)
#define SC_C4      (0x1.99343027bf8c3p-16)
#define SC_S1      (-0x1.555545995a603p-3)
#define SC_S2      (0x1.1107605230bc4p-7)
#define SC_S3      (-0x1.994eb3774cf24p-13)

__device__ __forceinline__ unsigned abstop12(float x) {
    return (__float_as_uint(x) >> 20) & 0x7ffu;
}

__device__ __forceinline__ float sp_sin(double x, double x2) {
    double x3 = __dmul_rn(x, x2);
    double s1 = __dadd_rn(SC_S2, __dmul_rn(x2, SC_S3));
    double x7 = __dmul_rn(x3, x2);
    double s  = __dadd_rn(x, __dmul_rn(x3, SC_S1));
    return (float)__dadd_rn(s, __dmul_rn(x7, s1));
}

__device__ __forceinline__ float sp_cos(double x2, bool neg) {
    double c0 = neg ? -SC_C0 : SC_C0;
    double c1 = neg ? -SC_C1 : SC_C1;
    double c2 = neg ? -SC_C2 : SC_C2;
    double c3 = neg ? -SC_C3 : SC_C3;
    double c4 = neg ? -SC_C4 : SC_C4;
    double x4  = __dmul_rn(x2, x2);
    double c2v = __dadd_rn(c3, __dmul_rn(x2, c4));
    double c1v = __dadd_rn(c0, __dmul_rn(x2, c1));
    double x6  = __dmul_rn(x4, x2);
    double c   = __dadd_rn(c1v, __dmul_rn(x4, c2));
    return (float)__dadd_rn(c, __dmul_rn(x6, c2v));
}

__device__ __forceinline__ double reduce_fast(double x, int* np) {
    double r = __dmul_rn(x, SC_HPI_INV);
    int n = (((int)r) + 0x800000) >> 24;
    *np = n;
    return __dsub_rn(x, __dmul_rn((double)n, SC_HPI));
}

__device__ __forceinline__ float glibc_sinf(float y) {
    unsigned at = abstop12(y);
    double x = (double)y;
    if (at < 0x3f4u) {                       // |y| < 0.78125
        if (at < 0x398u) return y;           // |y| < 0x1p-12
        return sp_sin(x, __dmul_rn(x, x));
    }
    int n;
    double r = reduce_fast(x, &n);
    double s = ((n + 1) & 2) ? -1.0 : 1.0;
    bool neg = (n & 2) != 0;
    double xs = __dmul_rn(r, s);
    double x2 = __dmul_rn(r, r);
    if ((n & 1) == 0) return sp_sin(xs, x2);
    return sp_cos(x2, neg);
}

__device__ __forceinline__ float glibc_cosf(float y) {
    unsigned at = abstop12(y);
    double x = (double)y;
    if (at < 0x3f4u) {
        if (at < 0x398u) return 1.0f;
        return sp_cos(__dmul_rn(x, x), false);
    }
    int n;
    double r = reduce_fast(x, &n);
    double s = ((n + 2) & 2) ? -1.0 : 1.0;
    bool neg = ((n + 1) & 2) != 0;
    int m = n ^ 1;
    double xs = __dmul_rn(r, s);
    double x2 = __dmul_rn(r, r);
    if ((m & 1) == 0) return sp_sin(xs, x2);
    return sp_cos(x2, neg);
}

// Merged: computes BOTH glibc_sinf(y) and glibc_cosf(y) with one reduce_fast.
// Bit-identical to the separate calls (reduce is deterministic; each result
// takes exactly the same sp_sin/sp_cos path with the same operands).
__device__ __forceinline__ void glibc_sincosf(float y, float& so, float& co) {
    unsigned at = abstop12(y);
    double x = (double)y;
    if (at < 0x3f4u) {
        if (at < 0x398u) { so = y; co = 1.0f; return; }
        double x2 = __dmul_rn(x, x);
        so = sp_sin(x, x2);
        co = sp_cos(x2, false);
        return;
    }
    int n;
    double r = reduce_fast(x, &n);
    double x2 = __dmul_rn(r, r);
    double ss = ((n + 1) & 2) ? -1.0 : 1.0;   // sin sign
    double cs = ((n + 2) & 2) ? -1.0 : 1.0;   // cos sign
    bool sneg = (n & 2) != 0;
    bool cneg = ((n + 1) & 2) != 0;
    if ((n & 1) == 0) {
        so = sp_sin(__dmul_rn(r, ss), x2);
        co = sp_cos(x2, cneg);
    } else {
        so = sp_cos(x2, sneg);
        co = sp_sin(__dmul_rn(r, cs), x2);
    }
}

// ===== f64 spherical bessel (for zeros/bnorm; replicates _sph_jn_np) =====
__device__ __forceinline__ double jn_f64(double x, int n) {
    double s = sin(x), c = cos(x);
    double j0 = s / x;
    if (n == 0) return j0;
    double j1 = s / (x * x) - c / x;
    double jm1 = j0, j = j1;
    for (int l = 1; l < n; ++l) {
        double t = (double)(2 * l + 1) / x * j - jm1;
        jm1 = j; j = t;
    }
    return j;
}

// cst layout (floats): [0..41] zf, [42..83] bnorm, [84..90] ynorm
__global__ __launch_bounds__(704) void setup_k(float* __restrict__ cst) {
    __shared__ double pts[13];
    __shared__ double roots[12];
    __shared__ double Z[NSPH][NRAD];
    const double PI = 3.141592653589793238462643383279502884;
    int tid = threadIdx.x, wv = tid >> 6, ln = tid & 63;
    if (tid < 12) pts[tid] = PI * (double)(tid + 1);
    __syncthreads();
    if (tid < NRAD) Z[0][tid] = pts[tid];
    for (int i = 1; i < NSPH; ++i) {
        int m = NRAD + NSPH - 1 - i;  // 12 - i
        if (wv < m) {
            double a = pts[wv], b = pts[wv + 1];
            for (int r = 0; r < 9; ++r) {
                double st = (b - a) * (1.0 / 63.0);
                double f = jn_f64(a + st * (double)ln, i);
                double f0 = __shfl(f, 0);
                unsigned long long bm = __ballot((ln > 0) && (f0 * f <= 0.0));
                int idx = bm ? (__ffsll((unsigned long long)bm) - 1) : 63;
                b = a + st * (double)idx;
                a = a + st * (double)(idx - 1);
            }
            if (ln == 0) roots[wv] = 0.5 * (a + b);
        }
        __syncthreads();
        if (tid < m) pts[tid] = roots[tid];
        if (tid < NRAD) Z[i][tid] = roots[tid];
        __syncthreads();
    }
    if (tid < NSPH * NRAD) {
        int l = tid / NRAD;
        double z = Z[l][tid % NRAD];
        cst[tid] = (float)z;
        double jp = jn_f64(z, l + 1);
        cst[42 + tid] = (float)(1.0 / sqrt(0.5 * (jp * jp)));
    }
    if (tid < NSPH) {
        cst[84 + tid] = (float)sqrt((double)(2 * tid + 1) / (4.0 * PI));
    }
}

// ===== Phase A: per-(edge, l, n) rbf_env table, bit-exact chain =====
__global__ __launch_bounds__(252) void edge_k(
    const float* __restrict__ D, const float* __restrict__ cst,
    float* __restrict__ tab, int nE)
{
    __shared__ float zf[42], bn[42];
    __shared__ float sh_d[EPB], sh_unc[EPB];
    int tid = threadIdx.x;
    if (tid < 42) { zf[tid] = cst[tid]; bn[tid] = cst[42 + tid]; }
    int le = tid / 42;
    int k  = tid - le * 42;
    long long e = (long long)blockIdx.x * EPB + le;
    bool ok = e < (long long)nE;
    if (ok && k == 0) {
        float d = __fmul_rn(D[e], 0.2f);
        float invd = __fdiv_rn(1.0f, d);
        float d2 = d * d, d4 = d2 * d2, d5 = d4 * d, d6 = d5 * d, d7 = d6 * d;
        float env = ((invd + (-28.0f) * d5) + 48.0f * d6) + (-21.0f) * d7;
        float u_d = (d < 1.0f) ? env : 0.0f;
        const float NC = (float)0.0894427190999916;  // 0.2**1.5
        sh_unc[le] = __fmul_rn(u_d, NC);
        sh_d[le] = d;
    }
    __syncthreads();
    if (!ok) return;
    float d = sh_d[le], unc = sh_unc[le];
    int l = k / 6;

    float x = __fmul_rn(d, zf[k]);
    float s, c;
    glibc_sincosf(x, s, c);   // one shared reduction; bit-exact vs sinf+cosf
    float j = __fdiv_rn(s, x);
    if (l > 0) {
        float x2 = __fmul_rn(x, x);
        float j1 = __fsub_rn(__fdiv_rn(s, x2), __fdiv_rn(c, x));
        float jm1 = j, jc = j1;
        for (int kk = 1; kk < l; ++kk) {
            float fk = __fdiv_rn((float)(2 * kk + 1), x);
            float jn2 = __fsub_rn(__fmul_rn(fk, jc), jm1);
            jm1 = jc; jc = jn2;
        }
        j = jc;
    }
    tab[e * NE_PAD + k] = __fmul_rn(unc, __fmul_rn(bn[k], j));
}

// ===== Phase B: gather + sph multiply; chunked LDS stage + NT coalesced =====
__global__ __launch_bounds__(BLK) void trip_k(
    const float* __restrict__ Ang, const int* __restrict__ id3,
    const float* __restrict__ tab, const float* __restrict__ cst,
    float* __restrict__ out, int nT)
{
    __shared__ float stg[CHUNK * 42];   // 21504 B -> ~7 blocks/CU
    int tid = threadIdx.x;
    int base = blockIdx.x * BLK;
    int t = base + tid;
    bool ok = t < nT;
    int e = ok ? __builtin_nontemporal_load(id3 + t) : 0;
    float ang = ok ? __builtin_nontemporal_load(Ang + t) : 0.0f;

    // issue the 42-float gather (latency hides under cosf/Legendre)
    const f32x4* rowv = (const f32x4*)(tab + (long long)e * NE_PAD);
    float row[42];
#pragma unroll
    for (int w = 0; w < 10; ++w) {
        f32x4 v = rowv[w];
        row[w * 4 + 0] = v.x; row[w * 4 + 1] = v.y;
        row[w * 4 + 2] = v.z; row[w * 4 + 3] = v.w;
    }
    {
        f32x2 v = ((const f32x2*)rowv)[20];
        row[40] = v.x; row[41] = v.y;
    }

    // identical numerics to rounds 3-6 (bit-exact output)
    float ct = glibc_cosf(ang);
    float P[NSPH];
    P[0] = 1.0f; P[1] = ct;
#pragma unroll
    for (int l = 1; l < NSPH - 1; ++l) {
        float t1 = __fmul_rn(__fmul_rn((float)(2 * l + 1), ct), P[l]);
        float t2 = __fmul_rn((float)l, P[l - 1]);
        P[l + 1] = __fdiv_rn(__fsub_rn(t1, t2), (float)(l + 1));
    }
    float yP[NSPH];
#pragma unroll
    for (int l = 0; l < NSPH; ++l) yP[l] = __fmul_rn(cst[84 + l], P[l]);
#pragma unroll
    for (int k = 0; k < 42; ++k) row[k] = __fmul_rn(row[k], yP[k / 6]);

    // ---- chunk 0: rows [0,128) ----
    if (tid < CHUNK) {
#pragma unroll
        for (int k = 0; k < 42; ++k) stg[tid * 42 + k] = row[k];
    }
    __syncthreads();
    {
        int nv = nT - base; if (nv > CHUNK) nv = CHUNK; if (nv < 0) nv = 0;
        int nf2 = nv * 21;
        const f32x2* src = (const f32x2*)stg;
        f32x2* dst = (f32x2*)(out + (long long)base * 42);
        for (int i = tid; i < nf2; i += BLK)
            __builtin_nontemporal_store(src[i], dst + i);
    }
    __syncthreads();
    // ---- chunk 1: rows [128,256) ----
    if (tid >= CHUNK) {
#pragma unroll
        for (int k = 0; k < 42; ++k) stg[(tid - CHUNK) * 42 + k] = row[k];
    }
    __syncthreads();
    {
        int base1 = base + CHUNK;
        int nv = nT - base1; if (nv > CHUNK) nv = CHUNK; if (nv < 0) nv = 0;
        int nf2 = nv * 21;
        const f32x2* src = (const f32x2*)stg;
        f32x2* dst = (f32x2*)(out + (long long)base1 * 42);
        for (int i = tid; i < nf2; i += BLK)
            __builtin_nontemporal_store(src[i], dst + i);
    }
}

// ===== fallback: round-3 fused kernel (used only if ws too small) =====
__global__ __launch_bounds__(BLK) void sph_main(
    const float* __restrict__ D, const float* __restrict__ Ang,
    const int* __restrict__ id3, const float* __restrict__ cst,
    float* __restrict__ out, int nT)
{
    __shared__ float zf[42], bn[42], yn[7];
    __shared__ float stg[BLK * 42];
    int tid = threadIdx.x;
    if (tid < 42) { zf[tid] = cst[tid]; bn[tid] = cst[42 + tid]; }
    if (tid < 7)  { yn[tid] = cst[84 + tid]; }
    __syncthreads();
    int base = blockIdx.x * BLK;
    int t = base + tid;
    bool ok = t < nT;
    int e = ok ? id3[t] : 0;
    float Dv = D[e];
    float ang = ok ? Ang[t] : 0.0f;
    float d = __fmul_rn(Dv, 0.2f);
    float invd = __fdiv_rn(1.0f, d);
    float d2 = d * d, d4 = d2 * d2, d5 = d4 * d, d6 = d5 * d, d7 = d6 * d;
    float env = ((invd + (-28.0f) * d5) + 48.0f * d6) + (-21.0f) * d7;
    float u_d = (d < 1.0f) ? env : 0.0f;
    const float NC = (float)0.0894427190999916;
    float unc = __fmul_rn(u_d, NC);
    float ct = glibc_cosf(ang);
    float P[NSPH];
    P[0] = 1.0f; P[1] = ct;
#pragma unroll
    for (int l = 1; l < NSPH - 1; ++l) {
        float t1 = __fmul_rn(__fmul_rn((float)(2 * l + 1), ct), P[l]);
        float t2 = __fmul_rn((float)l, P[l - 1]);
        P[l + 1] = __fdiv_rn(__fsub_rn(t1, t2), (float)(l + 1));
    }
    float* row = &stg[tid * 42];
#pragma unroll
    for (int l = 0; l < NSPH; ++l) {
        float yPl = __fmul_rn(yn[l], P[l]);
        for (int n = 0; n < NRAD; ++n) {
            float z = zf[l * 6 + n];
            float x = __fmul_rn(d, z);
            float s, c;
            glibc_sincosf(x, s, c);
            float j = __fdiv_rn(s, x);
            if (l > 0) {
                float x2 = __fmul_rn(x, x);
                float j1 = __fsub_rn(__fdiv_rn(s, x2), __fdiv_rn(c, x));
                float jm1 = j, jc = j1;
                for (int kk = 1; kk < l; ++kk) {
                    float fk = __fdiv_rn((float)(2 * kk + 1), x);
                    float jn2 = __fsub_rn(__fmul_rn(fk, jc), jm1);
                    jm1 = jc; jc = jn2;
                }
                j = jc;
            }
            float re = __fmul_rn(unc, __fmul_rn(bn[l * 6 + n], j));
            row[l * 6 + n] = __fmul_rn(re, yPl);
        }
    }
    __syncthreads();
    int nv = nT - base; if (nv > BLK) nv = BLK;
    int nf2 = nv * 21;
    const float2* src = (const float2*)stg;
    float2* dst = (float2*)(out + (long long)base * 42);
    for (int i = tid; i < nf2; i += BLK) dst[i] = src[i];
}

extern "C" void kernel_launch(void* const* d_in, const int* in_sizes, int n_in,
                              void* d_out, int out_size, void* d_ws, size_t ws_size,
                              hipStream_t stream) {
    const float* D   = (const float*)d_in[0];
    const float* Ang = (const float*)d_in[1];
    const int*   id3 = (const int*)d_in[2];
    float* out = (float*)d_out;
    int nE = in_sizes[0];
    int nT = in_sizes[1];

    size_t tab_bytes = (size_t)nE * NE_PAD * sizeof(float);
    if (ws_size >= tab_bytes + 512) {
        float* tab = (float*)d_ws;
        float* cst = (float*)((char*)d_ws + tab_bytes);
        setup_k<<<1, 704, 0, stream>>>(cst);
        int gA = (nE + EPB - 1) / EPB;
        edge_k<<<gA, 252, 0, stream>>>(D, cst, tab, nE);
        int gB = (nT + BLK - 1) / BLK;
        trip_k<<<gB, BLK, 0, stream>>>(Ang, id3, tab, cst, out, nT);
    } else {
        float* cst = (float*)d_ws;   // 91 floats
        setup_k<<<1, 704, 0, stream>>>(cst);
        int grid = (nT + BLK - 1) / BLK;
        sph_main<<<grid, BLK, 0, stream>>>(D, Ang, id3, cst, out, nT);
    }
}

// Round 8
// 284.889 us; speedup vs baseline: 3.9305x; 1.0561x over previous
//
#include <hip/hip_runtime.h>
#include <math.h>
#include <stdint.h>

#define NSPH 7
#define NRAD 6
#define BLK  256
#define CHUNK 128   // trip_k rows per LDS chunk
#define EPB  6      // edges per edge_k block (6*42 = 252 threads)
#define NE_PAD 48   // padded table row: 192 B = 12 x f32x4

typedef float f32x2 __attribute__((ext_vector_type(2)));
typedef float f32x4 __attribute__((ext_vector_type(4)));

// ===== glibc sinf/cosf bit-exact replication =====
// (glibc sysdeps/ieee754/flt-32, baseline x86-64: f64 internals, NO fma)
// verified PASS rounds 3-7.
#define SC_HPI_INV 0x1.45F306DC9C883p+23   /* 2/pi * 2^24 */
#define SC_HPI     0x1.921FB54442D18p+0
#define SC_C0      (0x1p+0)
#define SC_C1      (-0x1.ffffffd0c621cp-2)
#define SC_C2      (0x1.55553e1068f19p-5)
#define SC_C3      (-0x1.6c087e89a359dp-10)
#define SC_C4      (0x1.99343027bf8c3p-16)
#define SC_S1      (-0x1.555545995a603p-3)
#define SC_S2      (0x1.1107605230bc4p-7)
#define SC_S3      (-0x1.994eb3774cf24p-13)

__device__ __forceinline__ unsigned abstop12(float x) {
    return (__float_as_uint(x) >> 20) & 0x7ffu;
}

__device__ __forceinline__ float sp_sin(double x, double x2) {
    double x3 = __dmul_rn(x, x2);
    double s1 = __dadd_rn(SC_S2, __dmul_rn(x2, SC_S3));
    double x7 = __dmul_rn(x3, x2);
    double s  = __dadd_rn(x, __dmul_rn(x3, SC_S1));
    return (float)__dadd_rn(s, __dmul_rn(x7, s1));
}

__device__ __forceinline__ float sp_cos(double x2, bool neg) {
    double c0 = neg ? -SC_C0 : SC_C0;
    double c1 = neg ? -SC_C1 : SC_C1;
    double c2 = neg ? -SC_C2 : SC_C2;
    double c3 = neg ? -SC_C3 : SC_C3;
    double c4 = neg ? -SC_C4 : SC_C4;
    double x4  = __dmul_rn(x2, x2);
    double c2v = __dadd_rn(c3, __dmul_rn(x2, c4));
    double c1v = __dadd_rn(c0, __dmul_rn(x2, c1));
    double x6  = __dmul_rn(x4, x2);
    double c   = __dadd_rn(c1v, __dmul_rn(x4, c2));
    return (float)__dadd_rn(c, __dmul_rn(x6, c2v));
}

__device__ __forceinline__ double reduce_fast(double x, int* np) {
    double r = __dmul_rn(x, SC_HPI_INV);
    int n = (((int)r) + 0x800000) >> 24;
    *np = n;
    return __dsub_rn(x, __dmul_rn((double)n, SC_HPI));
}

__device__ __forceinline__ float glibc_cosf(float y) {
    unsigned at = abstop12(y);
    double x = (double)y;
    if (at < 0x3f4u) {
        if (at < 0x398u) return 1.0f;
        return sp_cos(__dmul_rn(x, x), false);
    }
    int n;
    double r = reduce_fast(x, &n);
    double s = ((n + 2) & 2) ? -1.0 : 1.0;
    bool neg = ((n + 1) & 2) != 0;
    int m = n ^ 1;
    double xs = __dmul_rn(r, s);
    double x2 = __dmul_rn(r, r);
    if ((m & 1) == 0) return sp_sin(xs, x2);
    return sp_cos(x2, neg);
}

// BOTH sinf(y) and cosf(y) with one reduce_fast; bit-identical to glibc calls.
__device__ __forceinline__ void glibc_sincosf(float y, float& so, float& co) {
    unsigned at = abstop12(y);
    double x = (double)y;
    if (at < 0x3f4u) {
        if (at < 0x398u) { so = y; co = 1.0f; return; }
        double x2 = __dmul_rn(x, x);
        so = sp_sin(x, x2);
        co = sp_cos(x2, false);
        return;
    }
    int n;
    double r = reduce_fast(x, &n);
    double x2 = __dmul_rn(r, r);
    double ss = ((n + 1) & 2) ? -1.0 : 1.0;
    double cs = ((n + 2) & 2) ? -1.0 : 1.0;
    bool sneg = (n & 2) != 0;
    bool cneg = ((n + 1) & 2) != 0;
    if ((n & 1) == 0) {
        so = sp_sin(__dmul_rn(r, ss), x2);
        co = sp_cos(x2, cneg);
    } else {
        so = sp_cos(x2, sneg);
        co = sp_sin(__dmul_rn(r, cs), x2);
    }
}

// ===== f64 spherical bessel (for zeros/bnorm; replicates _sph_jn_np) =====
__device__ __forceinline__ double jn_f64(double x, int n) {
    double s = sin(x), c = cos(x);
    double j0 = s / x;
    if (n == 0) return j0;
    double j1 = s / (x * x) - c / x;
    double jm1 = j0, j = j1;
    for (int l = 1; l < n; ++l) {
        double t = (double)(2 * l + 1) / x * j - jm1;
        jm1 = j; j = t;
    }
    return j;
}

// cst layout (floats): [0..41] zf, [42..83] bnorm, [84..90] ynorm
__global__ __launch_bounds__(704) void setup_k(float* __restrict__ cst) {
    __shared__ double pts[13];
    __shared__ double roots[12];
    __shared__ double Z[NSPH][NRAD];
    const double PI = 3.141592653589793238462643383279502884;
    int tid = threadIdx.x, wv = tid >> 6, ln = tid & 63;
    if (tid < 12) pts[tid] = PI * (double)(tid + 1);
    __syncthreads();
    if (tid < NRAD) Z[0][tid] = pts[tid];
    for (int i = 1; i < NSPH; ++i) {
        int m = NRAD + NSPH - 1 - i;  // 12 - i
        if (wv < m) {
            double a = pts[wv], b = pts[wv + 1];
            for (int r = 0; r < 9; ++r) {
                double st = (b - a) * (1.0 / 63.0);
                double f = jn_f64(a + st * (double)ln, i);
                double f0 = __shfl(f, 0);
                unsigned long long bm = __ballot((ln > 0) && (f0 * f <= 0.0));
                int idx = bm ? (__ffsll((unsigned long long)bm) - 1) : 63;
                b = a + st * (double)idx;
                a = a + st * (double)(idx - 1);
            }
            if (ln == 0) roots[wv] = 0.5 * (a + b);
        }
        __syncthreads();
        if (tid < m) pts[tid] = roots[tid];
        if (tid < NRAD) Z[i][tid] = roots[tid];
        __syncthreads();
    }
    if (tid < NSPH * NRAD) {
        int l = tid / NRAD;
        double z = Z[l][tid % NRAD];
        cst[tid] = (float)z;
        double jp = jn_f64(z, l + 1);
        cst[42 + tid] = (float)(1.0 / sqrt(0.5 * (jp * jp)));
    }
    if (tid < NSPH) {
        cst[84 + tid] = (float)sqrt((double)(2 * tid + 1) / (4.0 * PI));
    }
}

// ===== Phase A: rbf_env table; l-uniform waves (divergence-minimized) =====
// tid -> (l, edge, n): waves see l in {0-1},{1-3},{3-5},{5-6} -> short loops.
__global__ __launch_bounds__(252) void edge_k(
    const float* __restrict__ D, const float* __restrict__ cst,
    float* __restrict__ tab, int nE)
{
    __shared__ float zf[42], bn[42];
    __shared__ float sh_d[EPB], sh_unc[EPB];
    int tid = threadIdx.x;
    if (tid < 42) { zf[tid] = cst[tid]; bn[tid] = cst[42 + tid]; }
    int l   = tid / 36;          // 252 = 7 * 36
    int rem = tid - l * 36;
    int le  = rem / 6;
    int n   = rem - le * 6;
    int k   = l * 6 + n;
    long long e = (long long)blockIdx.x * EPB + le;
    bool ok = e < (long long)nE;
    if (ok && k == 0) {          // one thread per edge computes env
        float d = __fmul_rn(D[e], 0.2f);
        float invd = __fdiv_rn(1.0f, d);
        float d2 = d * d, d4 = d2 * d2, d5 = d4 * d, d6 = d5 * d, d7 = d6 * d;
        float env = ((invd + (-28.0f) * d5) + 48.0f * d6) + (-21.0f) * d7;
        float u_d = (d < 1.0f) ? env : 0.0f;
        const float NC = (float)0.0894427190999916;  // 0.2**1.5
        sh_unc[le] = __fmul_rn(u_d, NC);
        sh_d[le] = d;
    }
    __syncthreads();
    if (!ok) return;
    float d = sh_d[le], unc = sh_unc[le];

    float x = __fmul_rn(d, zf[k]);
    float s, c;
    glibc_sincosf(x, s, c);
    float j = __fdiv_rn(s, x);
    if (l > 0) {
        float x2 = __fmul_rn(x, x);
        float j1 = __fsub_rn(__fdiv_rn(s, x2), __fdiv_rn(c, x));
        float jm1 = j, jc = j1;
        for (int kk = 1; kk < l; ++kk) {
            float fk = __fdiv_rn((float)(2 * kk + 1), x);
            float jn2 = __fsub_rn(__fmul_rn(fk, jc), jm1);
            jm1 = jc; jc = jn2;
        }
        j = jc;
    }
    tab[e * NE_PAD + k] = __fmul_rn(unc, __fmul_rn(bn[k], j));
}

// ===== Phase B: wave-cooperative row gather + NT coalesced store =====
// 12 lanes fetch one row's 12 f32x4 (192B coalesced) -> LDS; yP multiply
// happens in the copy-out (same single __fmul_rn per element: bit-exact).
__global__ __launch_bounds__(BLK) void trip_k(
    const float* __restrict__ Ang, const int* __restrict__ id3,
    const float* __restrict__ tab, const float* __restrict__ cst,
    float* __restrict__ out, int nT)
{
    __shared__ f32x4 stg4[CHUNK * 12];   // 24576 B
    __shared__ int   esh[BLK];           //  1024 B
    __shared__ float ysh[BLK * 8];       //  8192 B   (~4 blocks/CU)
    int tid = threadIdx.x;
    int base = blockIdx.x * BLK;
    int t = base + tid;
    bool ok = t < nT;
    int e = ok ? __builtin_nontemporal_load(id3 + t) : 0;
    float ang = ok ? __builtin_nontemporal_load(Ang + t) : 0.0f;
    esh[tid] = e * 12;   // row offset in f32x4 units

    // per-triplet sph factors (identical numerics to rounds 3-7)
    float ct = glibc_cosf(ang);
    float P[NSPH];
    P[0] = 1.0f; P[1] = ct;
#pragma unroll
    for (int l = 1; l < NSPH - 1; ++l) {
        float t1 = __fmul_rn(__fmul_rn((float)(2 * l + 1), ct), P[l]);
        float t2 = __fmul_rn((float)l, P[l - 1]);
        P[l + 1] = __fdiv_rn(__fsub_rn(t1, t2), (float)(l + 1));
    }
#pragma unroll
    for (int l = 0; l < NSPH; ++l)
        ysh[tid * 8 + l] = __fmul_rn(cst[84 + l], P[l]);
    __syncthreads();

    const f32x4* tab4 = (const f32x4*)tab;
    const float* stgf = (const float*)stg4;
#pragma unroll
    for (int c = 0; c < 2; ++c) {
        // cooperative gather: slot = row*12 + word, fully coalesced per row
#pragma unroll
        for (int it = 0; it < 6; ++it) {
            int slot = tid + BLK * it;        // 0..1535
            int row  = slot / 12;
            int word = slot - row * 12;
            stg4[slot] = tab4[esh[c * CHUNK + row] + word];
        }
        __syncthreads();
        int cbase = base + c * CHUNK;
        int nv = nT - cbase; if (nv > CHUNK) nv = CHUNK; if (nv < 0) nv = 0;
        int nf2 = nv * 21;
        f32x2* dst = (f32x2*)out + (long long)cbase * 21;
        for (int i = tid; i < nf2; i += BLK) {
            int r = i / 21, p = i - r * 21;
            int l = p / 3;                     // == (2p)/6
            float ym = ysh[(c * CHUNK + r) * 8 + l];
            f32x2 v;
            v.x = __fmul_rn(stgf[r * 48 + 2 * p],     ym);
            v.y = __fmul_rn(stgf[r * 48 + 2 * p + 1], ym);
            __builtin_nontemporal_store(v, dst + i);
        }
        __syncthreads();
    }
}

// ===== fallback: fused kernel (used only if ws too small) =====
__global__ __launch_bounds__(BLK) void sph_main(
    const float* __restrict__ D, const float* __restrict__ Ang,
    const int* __restrict__ id3, const float* __restrict__ cst,
    float* __restrict__ out, int nT)
{
    __shared__ float zf[42], bn[42], yn[7];
    __shared__ float stg[BLK * 42];
    int tid = threadIdx.x;
    if (tid < 42) { zf[tid] = cst[tid]; bn[tid] = cst[42 + tid]; }
    if (tid < 7)  { yn[tid] = cst[84 + tid]; }
    __syncthreads();
    int base = blockIdx.x * BLK;
    int t = base + tid;
    bool ok = t < nT;
    int e = ok ? id3[t] : 0;
    float Dv = D[e];
    float ang = ok ? Ang[t] : 0.0f;
    float d = __fmul_rn(Dv, 0.2f);
    float invd = __fdiv_rn(1.0f, d);
    float d2 = d * d, d4 = d2 * d2, d5 = d4 * d, d6 = d5 * d, d7 = d6 * d;
    float env = ((invd + (-28.0f) * d5) + 48.0f * d6) + (-21.0f) * d7;
    float u_d = (d < 1.0f) ? env : 0.0f;
    const float NC = (float)0.0894427190999916;
    float unc = __fmul_rn(u_d, NC);
    float ct = glibc_cosf(ang);
    float P[NSPH];
    P[0] = 1.0f; P[1] = ct;
#pragma unroll
    for (int l = 1; l < NSPH - 1; ++l) {
        float t1 = __fmul_rn(__fmul_rn((float)(2 * l + 1), ct), P[l]);
        float t2 = __fmul_rn((float)l, P[l - 1]);
        P[l + 1] = __fdiv_rn(__fsub_rn(t1, t2), (float)(l + 1));
    }
    float* row = &stg[tid * 42];
#pragma unroll
    for (int l = 0; l < NSPH; ++l) {
        float yPl = __fmul_rn(yn[l], P[l]);
        for (int n = 0; n < NRAD; ++n) {
            float z = zf[l * 6 + n];
            float x = __fmul_rn(d, z);
            float s, c;
            glibc_sincosf(x, s, c);
            float j = __fdiv_rn(s, x);
            if (l > 0) {
                float x2 = __fmul_rn(x, x);
                float j1 = __fsub_rn(__fdiv_rn(s, x2), __fdiv_rn(c, x));
                float jm1 = j, jc = j1;
                for (int kk = 1; kk < l; ++kk) {
                    float fk = __fdiv_rn((float)(2 * kk + 1), x);
                    float jn2 = __fsub_rn(__fmul_rn(fk, jc), jm1);
                    jm1 = jc; jc = jn2;
                }
                j = jc;
            }
            float re = __fmul_rn(unc, __fmul_rn(bn[l * 6 + n], j));
            row[l * 6 + n] = __fmul_rn(re, yPl);
        }
    }
    __syncthreads();
    int nv = nT - base; if (nv > BLK) nv = BLK;
    int nf2 = nv * 21;
    const float2* src = (const float2*)stg;
    float2* dst = (float2*)(out + (long long)base * 42);
    for (int i = tid; i < nf2; i += BLK) dst[i] = src[i];
}

extern "C" void kernel_launch(void* const* d_in, const int* in_sizes, int n_in,
                              void* d_out, int out_size, void* d_ws, size_t ws_size,
                              hipStream_t stream) {
    const float* D   = (const float*)d_in[0];
    const float* Ang = (const float*)d_in[1];
    const int*   id3 = (const int*)d_in[2];
    float* out = (float*)d_out;
    int nE = in_sizes[0];
    int nT = in_sizes[1];

    size_t tab_bytes = (size_t)nE * NE_PAD * sizeof(float);
    if (ws_size >= tab_bytes + 512) {
        float* tab = (float*)d_ws;
        float* cst = (float*)((char*)d_ws + tab_bytes);
        setup_k<<<1, 704, 0, stream>>>(cst);
        int gA = (nE + EPB - 1) / EPB;
        edge_k<<<gA, 252, 0, stream>>>(D, cst, tab, nE);
        int gB = (nT + BLK - 1) / BLK;
        trip_k<<<gB, BLK, 0, stream>>>(Ang, id3, tab, cst, out, nT);
    } else {
        float* cst = (float*)d_ws;   // 91 floats
        setup_k<<<1, 704, 0, stream>>>(cst);
        int grid = (nT + BLK - 1) / BLK;
        sph_main<<<grid, BLK, 0, stream>>>(D, Ang, id3, cst, out, nT);
    }
}

// Round 9
// 284.330 us; speedup vs baseline: 3.9383x; 1.0020x over previous
//
#include <hip/hip_runtime.h>
#include <math.h>
#include <stdint.h>

#define NSPH 7
#define NRAD 6
#define BLK  256
#define EPB  6      // edges per edge_k block (252 threads)
#define NE_PAD 48   // padded table row: 192 B (64B-aligned rows)

typedef float f32x2 __attribute__((ext_vector_type(2)));
typedef float f32x4 __attribute__((ext_vector_type(4)));

// ===== glibc sinf/cosf bit-exact replication =====
// (glibc sysdeps/ieee754/flt-32, baseline x86-64: f64 internals, NO fma)
// verified PASS rounds 3-8.
#define SC_HPI_INV 0x1.45F306DC9C883p+23   /* 2/pi * 2^24 */
#define SC_HPI     0x1.921FB54442D18p+0
#define SC_C0      (0x1p+0)
#define SC_C1      (-0x1.ffffffd0c621cp-2)
#define SC_C2      (0x1.55553e1068f19p-5)
#define SC_C3      (-0x1.6c087e89a359dp-10)
#define SC_C4      (0x1.99343027bf8c3p-16)
#define SC_S1      (-0x1.555545995a603p-3)
#define SC_S2      (0x1.1107605230bc4p-7)
#define SC_S3      (-0x1.994eb3774cf24p-13)

__device__ __forceinline__ unsigned abstop12(float x) {
    return (__float_as_uint(x) >> 20) & 0x7ffu;
}

__device__ __forceinline__ float sp_sin(double x, double x2) {
    double x3 = __dmul_rn(x, x2);
    double s1 = __dadd_rn(SC_S2, __dmul_rn(x2, SC_S3));
    double x7 = __dmul_rn(x3, x2);
    double s  = __dadd_rn(x, __dmul_rn(x3, SC_S1));
    return (float)__dadd_rn(s, __dmul_rn(x7, s1));
}

__device__ __forceinline__ float sp_cos(double x2, bool neg) {
    double c0 = neg ? -SC_C0 : SC_C0;
    double c1 = neg ? -SC_C1 : SC_C1;
    double c2 = neg ? -SC_C2 : SC_C2;
    double c3 = neg ? -SC_C3 : SC_C3;
    double c4 = neg ? -SC_C4 : SC_C4;
    double x4  = __dmul_rn(x2, x2);
    double c2v = __dadd_rn(c3, __dmul_rn(x2, c4));
    double c1v = __dadd_rn(c0, __dmul_rn(x2, c1));
    double x6  = __dmul_rn(x4, x2);
    double c   = __dadd_rn(c1v, __dmul_rn(x4, c2));
    return (float)__dadd_rn(c, __dmul_rn(x6, c2v));
}

__device__ __forceinline__ double reduce_fast(double x, int* np) {
    double r = __dmul_rn(x, SC_HPI_INV);
    int n = (((int)r) + 0x800000) >> 24;
    *np = n;
    return __dsub_rn(x, __dmul_rn((double)n, SC_HPI));
}

__device__ __forceinline__ float glibc_cosf(float y) {
    unsigned at = abstop12(y);
    double x = (double)y;
    if (at < 0x3f4u) {
        if (at < 0x398u) return 1.0f;
        return sp_cos(__dmul_rn(x, x), false);
    }
    int n;
    double r = reduce_fast(x, &n);
    double s = ((n + 2) & 2) ? -1.0 : 1.0;
    bool neg = ((n + 1) & 2) != 0;
    int m = n ^ 1;
    double xs = __dmul_rn(r, s);
    double x2 = __dmul_rn(r, r);
    if ((m & 1) == 0) return sp_sin(xs, x2);
    return sp_cos(x2, neg);
}

// BOTH sinf(y) and cosf(y) with one reduce_fast; bit-identical to glibc calls.
__device__ __forceinline__ void glibc_sincosf(float y, float& so, float& co) {
    unsigned at = abstop12(y);
    double x = (double)y;
    if (at < 0x3f4u) {
        if (at < 0x398u) { so = y; co = 1.0f; return; }
        double x2 = __dmul_rn(x, x);
        so = sp_sin(x, x2);
        co = sp_cos(x2, false);
        return;
    }
    int n;
    double r = reduce_fast(x, &n);
    double x2 = __dmul_rn(r, r);
    double ss = ((n + 1) & 2) ? -1.0 : 1.0;
    double cs = ((n + 2) & 2) ? -1.0 : 1.0;
    bool sneg = (n & 2) != 0;
    bool cneg = ((n + 1) & 2) != 0;
    if ((n & 1) == 0) {
        so = sp_sin(__dmul_rn(r, ss), x2);
        co = sp_cos(x2, cneg);
    } else {
        so = sp_cos(x2, sneg);
        co = sp_sin(__dmul_rn(r, cs), x2);
    }
}

// ===== f64 spherical bessel (for zeros/bnorm; replicates _sph_jn_np) =====
__device__ __forceinline__ double jn_f64(double x, int n) {
    double s = sin(x), c = cos(x);
    double j0 = s / x;
    if (n == 0) return j0;
    double j1 = s / (x * x) - c / x;
    double jm1 = j0, j = j1;
    for (int l = 1; l < n; ++l) {
        double t = (double)(2 * l + 1) / x * j - jm1;
        jm1 = j; j = t;
    }
    return j;
}

// cst layout (floats): [0..41] zf, [42..83] bnorm, [84..90] ynorm
__global__ __launch_bounds__(704) void setup_k(float* __restrict__ cst) {
    __shared__ double pts[13];
    __shared__ double roots[12];
    __shared__ double Z[NSPH][NRAD];
    const double PI = 3.141592653589793238462643383279502884;
    int tid = threadIdx.x, wv = tid >> 6, ln = tid & 63;
    if (tid < 12) pts[tid] = PI * (double)(tid + 1);
    __syncthreads();
    if (tid < NRAD) Z[0][tid] = pts[tid];
    for (int i = 1; i < NSPH; ++i) {
        int m = NRAD + NSPH - 1 - i;  // 12 - i
        if (wv < m) {
            double a = pts[wv], b = pts[wv + 1];
            for (int r = 0; r < 9; ++r) {
                double st = (b - a) * (1.0 / 63.0);
                double f = jn_f64(a + st * (double)ln, i);
                double f0 = __shfl(f, 0);
                unsigned long long bm = __ballot((ln > 0) && (f0 * f <= 0.0));
                int idx = bm ? (__ffsll((unsigned long long)bm) - 1) : 63;
                b = a + st * (double)idx;
                a = a + st * (double)(idx - 1);
            }
            if (ln == 0) roots[wv] = 0.5 * (a + b);
        }
        __syncthreads();
        if (tid < m) pts[tid] = roots[tid];
        if (tid < NRAD) Z[i][tid] = roots[tid];
        __syncthreads();
    }
    if (tid < NSPH * NRAD) {
        int l = tid / NRAD;
        double z = Z[l][tid % NRAD];
        cst[tid] = (float)z;
        double jp = jn_f64(z, l + 1);
        cst[42 + tid] = (float)(1.0 / sqrt(0.5 * (jp * jp)));
    }
    if (tid < NSPH) {
        cst[84 + tid] = (float)sqrt((double)(2 * tid + 1) / (4.0 * PI));
    }
}

// ===== Phase A: rbf_env table; l-uniform waves (UNCHANGED from round 8) ====
__global__ __launch_bounds__(252) void edge_k(
    const float* __restrict__ D, const float* __restrict__ cst,
    float* __restrict__ tab, int nE)
{
    __shared__ float zf[42], bn[42];
    __shared__ float sh_d[EPB], sh_unc[EPB];
    int tid = threadIdx.x;
    if (tid < 42) { zf[tid] = cst[tid]; bn[tid] = cst[42 + tid]; }
    int l   = tid / 36;          // 252 = 7 * 36
    int rem = tid - l * 36;
    int le  = rem / 6;
    int n   = rem - le * 6;
    int k   = l * 6 + n;
    long long e = (long long)blockIdx.x * EPB + le;
    bool ok = e < (long long)nE;
    if (ok && k == 0) {
        float d = __fmul_rn(D[e], 0.2f);
        float invd = __fdiv_rn(1.0f, d);
        float d2 = d * d, d4 = d2 * d2, d5 = d4 * d, d6 = d5 * d, d7 = d6 * d;
        float env = ((invd + (-28.0f) * d5) + 48.0f * d6) + (-21.0f) * d7;
        float u_d = (d < 1.0f) ? env : 0.0f;
        const float NC = (float)0.0894427190999916;  // 0.2**1.5
        sh_unc[le] = __fmul_rn(u_d, NC);
        sh_d[le] = d;
    }
    __syncthreads();
    if (!ok) return;
    float d = sh_d[le], unc = sh_unc[le];

    float x = __fmul_rn(d, zf[k]);
    float s, c;
    glibc_sincosf(x, s, c);
    float j = __fdiv_rn(s, x);
    if (l > 0) {
        float x2 = __fmul_rn(x, x);
        float j1 = __fsub_rn(__fdiv_rn(s, x2), __fdiv_rn(c, x));
        float jm1 = j, jc = j1;
        for (int kk = 1; kk < l; ++kk) {
            float fk = __fdiv_rn((float)(2 * kk + 1), x);
            float jn2 = __fsub_rn(__fmul_rn(fk, jc), jm1);
            jm1 = jc; jc = jn2;
        }
        j = jc;
    }
    tab[e * NE_PAD + k] = __fmul_rn(unc, __fmul_rn(bn[k], j));
}

// ===== Phase B: direct streamed gather->mul->NT store (no LDS staging) ====
// Output f32x2 element i of the block's slab: row r=i/21, pair p=i%21.
// Consecutive lanes read consecutive 8B words of the same (random) table row
// -> wave footprint = ~3 contiguous 168B spans; stores fully coalesced.
__global__ __launch_bounds__(BLK) void trip_k(
    const float* __restrict__ Ang, const int* __restrict__ id3,
    const float* __restrict__ tab, const float* __restrict__ cst,
    float* __restrict__ out, int nT)
{
    __shared__ int   esh[BLK];       // 1 KB
    __shared__ float ysh[BLK * 8];   // 8 KB  -> 8 blocks/CU (wave-capped)
    int tid = threadIdx.x;
    int base = blockIdx.x * BLK;
    int t = base + tid;
    bool ok = t < nT;
    int e = ok ? __builtin_nontemporal_load(id3 + t) : 0;
    float ang = ok ? __builtin_nontemporal_load(Ang + t) : 0.0f;
    esh[tid] = e * 24;   // row offset in f32x2 units (48 floats)

    // per-triplet sph factors (identical numerics to rounds 3-8)
    float ct = glibc_cosf(ang);
    float P[NSPH];
    P[0] = 1.0f; P[1] = ct;
#pragma unroll
    for (int l = 1; l < NSPH - 1; ++l) {
        float t1 = __fmul_rn(__fmul_rn((float)(2 * l + 1), ct), P[l]);
        float t2 = __fmul_rn((float)l, P[l - 1]);
        P[l + 1] = __fdiv_rn(__fsub_rn(t1, t2), (float)(l + 1));
    }
#pragma unroll
    for (int l = 0; l < NSPH; ++l)
        ysh[tid * 8 + l] = __fmul_rn(cst[84 + l], P[l]);
    __syncthreads();

    const f32x2* tab2 = (const f32x2*)tab;
    f32x2* dst = (f32x2*)out + (long long)base * 21;
    int nv = nT - base; if (nv > BLK) nv = BLK;
    if (nv == BLK) {
#pragma unroll
        for (int it = 0; it < 21; ++it) {
            int i = tid + it * BLK;
            int r = i / 21, p = i - r * 21;
            f32x2 v = tab2[esh[r] + p];
            float ym = ysh[r * 8 + p / 3];
            f32x2 w;
            w.x = __fmul_rn(v.x, ym);
            w.y = __fmul_rn(v.y, ym);
            __builtin_nontemporal_store(w, dst + i);
        }
    } else {
        int nf2 = nv * 21; if (nf2 < 0) nf2 = 0;
        for (int i = tid; i < nf2; i += BLK) {
            int r = i / 21, p = i - r * 21;
            f32x2 v = tab2[esh[r] + p];
            float ym = ysh[r * 8 + p / 3];
            f32x2 w;
            w.x = __fmul_rn(v.x, ym);
            w.y = __fmul_rn(v.y, ym);
            __builtin_nontemporal_store(w, dst + i);
        }
    }
}

// ===== fallback: fused kernel (used only if ws too small) =====
__global__ __launch_bounds__(BLK) void sph_main(
    const float* __restrict__ D, const float* __restrict__ Ang,
    const int* __restrict__ id3, const float* __restrict__ cst,
    float* __restrict__ out, int nT)
{
    __shared__ float zf[42], bn[42], yn[7];
    __shared__ float stg[BLK * 42];
    int tid = threadIdx.x;
    if (tid < 42) { zf[tid] = cst[tid]; bn[tid] = cst[42 + tid]; }
    if (tid < 7)  { yn[tid] = cst[84 + tid]; }
    __syncthreads();
    int base = blockIdx.x * BLK;
    int t = base + tid;
    bool ok = t < nT;
    int e = ok ? id3[t] : 0;
    float Dv = D[e];
    float ang = ok ? Ang[t] : 0.0f;
    float d = __fmul_rn(Dv, 0.2f);
    float invd = __fdiv_rn(1.0f, d);
    float d2 = d * d, d4 = d2 * d2, d5 = d4 * d, d6 = d5 * d, d7 = d6 * d;
    float env = ((invd + (-28.0f) * d5) + 48.0f * d6) + (-21.0f) * d7;
    float u_d = (d < 1.0f) ? env : 0.0f;
    const float NC = (float)0.0894427190999916;
    float unc = __fmul_rn(u_d, NC);
    float ct = glibc_cosf(ang);
    float P[NSPH];
    P[0] = 1.0f; P[1] = ct;
#pragma unroll
    for (int l = 1; l < NSPH - 1; ++l) {
        float t1 = __fmul_rn(__fmul_rn((float)(2 * l + 1), ct), P[l]);
        float t2 = __fmul_rn((float)l, P[l - 1]);
        P[l + 1] = __fdiv_rn(__fsub_rn(t1, t2), (float)(l + 1));
    }
    float* row = &stg[tid * 42];
#pragma unroll
    for (int l = 0; l < NSPH; ++l) {
        float yPl = __fmul_rn(yn[l], P[l]);
        for (int n = 0; n < NRAD; ++n) {
            float z = zf[l * 6 + n];
            float x = __fmul_rn(d, z);
            float s, c;
            glibc_sincosf(x, s, c);
            float j = __fdiv_rn(s, x);
            if (l > 0) {
                float x2 = __fmul_rn(x, x);
                float j1 = __fsub_rn(__fdiv_rn(s, x2), __fdiv_rn(c, x));
                float jm1 = j, jc = j1;
                for (int kk = 1; kk < l; ++kk) {
                    float fk = __fdiv_rn((float)(2 * kk + 1), x);
                    float jn2 = __fsub_rn(__fmul_rn(fk, jc), jm1);
                    jm1 = jc; jc = jn2;
                }
                j = jc;
            }
            float re = __fmul_rn(unc, __fmul_rn(bn[l * 6 + n], j));
            row[l * 6 + n] = __fmul_rn(re, yPl);
        }
    }
    __syncthreads();
    int nv = nT - base; if (nv > BLK) nv = BLK;
    int nf2 = nv * 21;
    const float2* src = (const float2*)stg;
    float2* dst = (float2*)(out + (long long)base * 42);
    for (int i = tid; i < nf2; i += BLK) dst[i] = src[i];
}

extern "C" void kernel_launch(void* const* d_in, const int* in_sizes, int n_in,
                              void* d_out, int out_size, void* d_ws, size_t ws_size,
                              hipStream_t stream) {
    const float* D   = (const float*)d_in[0];
    const float* Ang = (const float*)d_in[1];
    const int*   id3 = (const int*)d_in[2];
    float* out = (float*)d_out;
    int nE = in_sizes[0];
    int nT = in_sizes[1];

    size_t tab_bytes = (size_t)nE * NE_PAD * sizeof(float);
    if (ws_size >= tab_bytes + 512) {
        float* tab = (float*)d_ws;
        float* cst = (float*)((char*)d_ws + tab_bytes);
        setup_k<<<1, 704, 0, stream>>>(cst);
        int gA = (nE + EPB - 1) / EPB;
        edge_k<<<gA, 252, 0, stream>>>(D, cst, tab, nE);
        int gB = (nT + BLK - 1) / BLK;
        trip_k<<<gB, BLK, 0, stream>>>(Ang, id3, tab, cst, out, nT);
    } else {
        float* cst = (float*)d_ws;   // 91 floats
        setup_k<<<1, 704, 0, stream>>>(cst);
        int grid = (nT + BLK - 1) / BLK;
        sph_main<<<grid, BLK, 0, stream>>>(D, Ang, id3, cst, out, nT);
    }
}

// Round 10
// 264.611 us; speedup vs baseline: 4.2317x; 1.0745x over previous
//
#include <hip/hip_runtime.h>
#include <math.h>
#include <stdint.h>

#define NSPH 7
#define NRAD 6
#define BLK  256
#define EPB  6      // edges per edge_k block (252 threads)
#define NE_PAD 48   // padded table row: 192 B (64B-aligned rows)

typedef float f32x2 __attribute__((ext_vector_type(2)));
typedef float f32x4 __attribute__((ext_vector_type(4)));

// ===== glibc sinf/cosf bit-exact replication =====
// (glibc sysdeps/ieee754/flt-32, baseline x86-64: f64 internals, NO fma)
// verified PASS rounds 3-9.
#define SC_HPI_INV 0x1.45F306DC9C883p+23   /* 2/pi * 2^24 */
#define SC_HPI     0x1.921FB54442D18p+0
#define SC_C0      (0x1p+0)
#define SC_C1      (-0x1.ffffffd0c621cp-2)
#define SC_C2      (0x1.55553e1068f19p-5)
#define SC_C3      (-0x1.6c087e89a359dp-10)
#define SC_C4      (0x1.99343027bf8c3p-16)
#define SC_S1      (-0x1.555545995a603p-3)
#define SC_S2      (0x1.1107605230bc4p-7)
#define SC_S3      (-0x1.994eb3774cf24p-13)

__device__ __forceinline__ unsigned abstop12(float x) {
    return (__float_as_uint(x) >> 20) & 0x7ffu;
}

__device__ __forceinline__ float sp_sin(double x, double x2) {
    double x3 = __dmul_rn(x, x2);
    double s1 = __dadd_rn(SC_S2, __dmul_rn(x2, SC_S3));
    double x7 = __dmul_rn(x3, x2);
    double s  = __dadd_rn(x, __dmul_rn(x3, SC_S1));
    return (float)__dadd_rn(s, __dmul_rn(x7, s1));
}

__device__ __forceinline__ float sp_cos(double x2, bool neg) {
    double c0 = neg ? -SC_C0 : SC_C0;
    double c1 = neg ? -SC_C1 : SC_C1;
    double c2 = neg ? -SC_C2 : SC_C2;
    double c3 = neg ? -SC_C3 : SC_C3;
    double c4 = neg ? -SC_C4 : SC_C4;
    double x4  = __dmul_rn(x2, x2);
    double c2v = __dadd_rn(c3, __dmul_rn(x2, c4));
    double c1v = __dadd_rn(c0, __dmul_rn(x2, c1));
    double x6  = __dmul_rn(x4, x2);
    double c   = __dadd_rn(c1v, __dmul_rn(x4, c2));
    return (float)__dadd_rn(c, __dmul_rn(x6, c2v));
}

// positive-coefficient cosine poly (sp_cos(x2,false))
__device__ __forceinline__ float sp_cos_pos(double x2) {
    double x4  = __dmul_rn(x2, x2);
    double c2v = __dadd_rn(SC_C3, __dmul_rn(x2, SC_C4));
    double c1v = __dadd_rn(SC_C0, __dmul_rn(x2, SC_C1));
    double x6  = __dmul_rn(x4, x2);
    double c   = __dadd_rn(c1v, __dmul_rn(x4, SC_C2));
    return (float)__dadd_rn(c, __dmul_rn(x6, c2v));
}

__device__ __forceinline__ double reduce_fast(double x, int* np) {
    double r = __dmul_rn(x, SC_HPI_INV);
    int n = (((int)r) + 0x800000) >> 24;
    *np = n;
    return __dsub_rn(x, __dmul_rn((double)n, SC_HPI));
}

__device__ __forceinline__ float glibc_cosf(float y) {
    unsigned at = abstop12(y);
    double x = (double)y;
    if (at < 0x3f4u) {
        if (at < 0x398u) return 1.0f;
        return sp_cos(__dmul_rn(x, x), false);
    }
    int n;
    double r = reduce_fast(x, &n);
    double s = ((n + 2) & 2) ? -1.0 : 1.0;
    bool neg = ((n + 1) & 2) != 0;
    int m = n ^ 1;
    double xs = __dmul_rn(r, s);
    double x2 = __dmul_rn(r, r);
    if ((m & 1) == 0) return sp_sin(xs, x2);
    return sp_cos(x2, neg);
}

// BOTH sinf(y) and cosf(y) with one reduce_fast; bit-identical to glibc calls.
__device__ __forceinline__ void glibc_sincosf(float y, float& so, float& co) {
    unsigned at = abstop12(y);
    double x = (double)y;
    if (at < 0x3f4u) {
        if (at < 0x398u) { so = y; co = 1.0f; return; }
        double x2 = __dmul_rn(x, x);
        so = sp_sin(x, x2);
        co = sp_cos(x2, false);
        return;
    }
    int n;
    double r = reduce_fast(x, &n);
    double x2 = __dmul_rn(r, r);
    double ss = ((n + 1) & 2) ? -1.0 : 1.0;
    double cs = ((n + 2) & 2) ? -1.0 : 1.0;
    bool sneg = (n & 2) != 0;
    bool cneg = ((n + 1) & 2) != 0;
    if ((n & 1) == 0) {
        so = sp_sin(__dmul_rn(r, ss), x2);
        co = sp_cos(x2, cneg);
    } else {
        so = sp_cos(x2, sneg);
        co = sp_sin(__dmul_rn(r, cs), x2);
    }
}

// Branch-free sincos for 2^-12 < x < 0.78125..117435 range (edge_k's x).
// Bit-identical to glibc_sincosf there:
//  - small-x branch == reduce path with n=0 (r=x exactly, same polys)
//  - sign application via f32 sign-bit XOR == f64 coeff/arg negation
//    (IEEE RN is odd-symmetric; f64->f32 convert commutes with negation)
__device__ __forceinline__ void sincos_nr(float y, float& so, float& co) {
    int n;
    double r = reduce_fast((double)y, &n);
    double x2 = __dmul_rn(r, r);
    float sps = sp_sin(r, x2);      // sin(r) rounded to f32
    float spc = sp_cos_pos(x2);     // cos(r) rounded to f32
    unsigned sbit = (unsigned)(n & 2) << 30;          // sin negative iff n&2
    unsigned cbit = (unsigned)((n + 1) & 2) << 30;    // cos negative iff (n+1)&2
    bool odd = (n & 1) != 0;
    float sv = odd ? spc : sps;
    float cv = odd ? sps : spc;
    so = __uint_as_float(__float_as_uint(sv) ^ sbit);
    co = __uint_as_float(__float_as_uint(cv) ^ cbit);
}

// ===== f64 spherical bessel (for zeros/bnorm; replicates _sph_jn_np) =====
__device__ __forceinline__ double jn_f64(double x, int n) {
    double s = sin(x), c = cos(x);
    double j0 = s / x;
    if (n == 0) return j0;
    double j1 = s / (x * x) - c / x;
    double jm1 = j0, j = j1;
    for (int l = 1; l < n; ++l) {
        double t = (double)(2 * l + 1) / x * j - jm1;
        jm1 = j; j = t;
    }
    return j;
}

// cst layout (floats): [0..41] zf, [42..83] bnorm, [84..90] ynorm
__global__ __launch_bounds__(704) void setup_k(float* __restrict__ cst) {
    __shared__ double pts[13];
    __shared__ double roots[12];
    __shared__ double Z[NSPH][NRAD];
    const double PI = 3.141592653589793238462643383279502884;
    int tid = threadIdx.x, wv = tid >> 6, ln = tid & 63;
    if (tid < 12) pts[tid] = PI * (double)(tid + 1);
    __syncthreads();
    if (tid < NRAD) Z[0][tid] = pts[tid];
    for (int i = 1; i < NSPH; ++i) {
        int m = NRAD + NSPH - 1 - i;  // 12 - i
        if (wv < m) {
            double a = pts[wv], b = pts[wv + 1];
            for (int r = 0; r < 9; ++r) {
                double st = (b - a) * (1.0 / 63.0);
                double f = jn_f64(a + st * (double)ln, i);
                double f0 = __shfl(f, 0);
                unsigned long long bm = __ballot((ln > 0) && (f0 * f <= 0.0));
                int idx = bm ? (__ffsll((unsigned long long)bm) - 1) : 63;
                b = a + st * (double)idx;
                a = a + st * (double)(idx - 1);
            }
            if (ln == 0) roots[wv] = 0.5 * (a + b);
        }
        __syncthreads();
        if (tid < m) pts[tid] = roots[tid];
        if (tid < NRAD) Z[i][tid] = roots[tid];
        __syncthreads();
    }
    if (tid < NSPH * NRAD) {
        int l = tid / NRAD;
        double z = Z[l][tid % NRAD];
        cst[tid] = (float)z;
        double jp = jn_f64(z, l + 1);
        cst[42 + tid] = (float)(1.0 / sqrt(0.5 * (jp * jp)));
    }
    if (tid < NSPH) {
        cst[84 + tid] = (float)sqrt((double)(2 * tid + 1) / (4.0 * PI));
    }
}

// ===== Phase A: rbf_env table; l-uniform waves; branch-free trig =====
__global__ __launch_bounds__(252) void edge_k(
    const float* __restrict__ D, const float* __restrict__ cst,
    float* __restrict__ tab, int nE)
{
    __shared__ float zf[42], bn[42];
    __shared__ float sh_d[EPB], sh_unc[EPB];
    int tid = threadIdx.x;
    if (tid < 42) { zf[tid] = cst[tid]; bn[tid] = cst[42 + tid]; }
    int l   = tid / 36;          // 252 = 7 * 36
    int rem = tid - l * 36;
    int le  = rem / 6;
    int n   = rem - le * 6;
    int k   = l * 6 + n;
    long long e = (long long)blockIdx.x * EPB + le;
    bool ok = e < (long long)nE;
    if (ok && k == 0) {
        float d = __fmul_rn(D[e], 0.2f);
        float invd = __fdiv_rn(1.0f, d);
        float d2 = d * d, d4 = d2 * d2, d5 = d4 * d, d6 = d5 * d, d7 = d6 * d;
        float env = ((invd + (-28.0f) * d5) + 48.0f * d6) + (-21.0f) * d7;
        float u_d = (d < 1.0f) ? env : 0.0f;
        const float NC = (float)0.0894427190999916;  // 0.2**1.5
        sh_unc[le] = __fmul_rn(u_d, NC);
        sh_d[le] = d;
    }
    __syncthreads();
    if (!ok) return;
    float d = sh_d[le], unc = sh_unc[le];

    float x = __fmul_rn(d, zf[k]);   // x in (0.0063, 26.9): sincos_nr valid
    float s, c;
    sincos_nr(x, s, c);
    float j = __fdiv_rn(s, x);
    if (l > 0) {
        float x2 = __fmul_rn(x, x);
        float j1 = __fsub_rn(__fdiv_rn(s, x2), __fdiv_rn(c, x));
        float jm1 = j, jc = j1;
        for (int kk = 1; kk < l; ++kk) {
            float fk = __fdiv_rn((float)(2 * kk + 1), x);
            float jn2 = __fsub_rn(__fmul_rn(fk, jc), jm1);
            jm1 = jc; jc = jn2;
        }
        j = jc;
    }
    tab[e * NE_PAD + k] = __fmul_rn(unc, __fmul_rn(bn[k], j));
}

// ===== Phase B: direct streamed gather->mul->NT store (UNCHANGED r9) ====
__global__ __launch_bounds__(BLK) void trip_k(
    const float* __restrict__ Ang, const int* __restrict__ id3,
    const float* __restrict__ tab, const float* __restrict__ cst,
    float* __restrict__ out, int nT)
{
    __shared__ int   esh[BLK];       // 1 KB
    __shared__ float ysh[BLK * 8];   // 8 KB
    int tid = threadIdx.x;
    int base = blockIdx.x * BLK;
    int t = base + tid;
    bool ok = t < nT;
    int e = ok ? __builtin_nontemporal_load(id3 + t) : 0;
    float ang = ok ? __builtin_nontemporal_load(Ang + t) : 0.0f;
    esh[tid] = e * 24;   // row offset in f32x2 units (48 floats)

    float ct = glibc_cosf(ang);
    float P[NSPH];
    P[0] = 1.0f; P[1] = ct;
#pragma unroll
    for (int l = 1; l < NSPH - 1; ++l) {
        float t1 = __fmul_rn(__fmul_rn((float)(2 * l + 1), ct), P[l]);
        float t2 = __fmul_rn((float)l, P[l - 1]);
        P[l + 1] = __fdiv_rn(__fsub_rn(t1, t2), (float)(l + 1));
    }
#pragma unroll
    for (int l = 0; l < NSPH; ++l)
        ysh[tid * 8 + l] = __fmul_rn(cst[84 + l], P[l]);
    __syncthreads();

    const f32x2* tab2 = (const f32x2*)tab;
    f32x2* dst = (f32x2*)out + (long long)base * 21;
    int nv = nT - base; if (nv > BLK) nv = BLK;
    if (nv == BLK) {
#pragma unroll
        for (int it = 0; it < 21; ++it) {
            int i = tid + it * BLK;
            int r = i / 21, p = i - r * 21;
            f32x2 v = tab2[esh[r] + p];
            float ym = ysh[r * 8 + p / 3];
            f32x2 w;
            w.x = __fmul_rn(v.x, ym);
            w.y = __fmul_rn(v.y, ym);
            __builtin_nontemporal_store(w, dst + i);
        }
    } else {
        int nf2 = nv * 21; if (nf2 < 0) nf2 = 0;
        for (int i = tid; i < nf2; i += BLK) {
            int r = i / 21, p = i - r * 21;
            f32x2 v = tab2[esh[r] + p];
            float ym = ysh[r * 8 + p / 3];
            f32x2 w;
            w.x = __fmul_rn(v.x, ym);
            w.y = __fmul_rn(v.y, ym);
            __builtin_nontemporal_store(w, dst + i);
        }
    }
}

// ===== fallback: fused kernel (used only if ws too small) =====
__global__ __launch_bounds__(BLK) void sph_main(
    const float* __restrict__ D, const float* __restrict__ Ang,
    const int* __restrict__ id3, const float* __restrict__ cst,
    float* __restrict__ out, int nT)
{
    __shared__ float zf[42], bn[42], yn[7];
    __shared__ float stg[BLK * 42];
    int tid = threadIdx.x;
    if (tid < 42) { zf[tid] = cst[tid]; bn[tid] = cst[42 + tid]; }
    if (tid < 7)  { yn[tid] = cst[84 + tid]; }
    __syncthreads();
    int base = blockIdx.x * BLK;
    int t = base + tid;
    bool ok = t < nT;
    int e = ok ? id3[t] : 0;
    float Dv = D[e];
    float ang = ok ? Ang[t] : 0.0f;
    float d = __fmul_rn(Dv, 0.2f);
    float invd = __fdiv_rn(1.0f, d);
    float d2 = d * d, d4 = d2 * d2, d5 = d4 * d, d6 = d5 * d, d7 = d6 * d;
    float env = ((invd + (-28.0f) * d5) + 48.0f * d6) + (-21.0f) * d7;
    float u_d = (d < 1.0f) ? env : 0.0f;
    const float NC = (float)0.0894427190999916;
    float unc = __fmul_rn(u_d, NC);
    float ct = glibc_cosf(ang);
    float P[NSPH];
    P[0] = 1.0f; P[1] = ct;
#pragma unroll
    for (int l = 1; l < NSPH - 1; ++l) {
        float t1 = __fmul_rn(__fmul_rn((float)(2 * l + 1), ct), P[l]);
        float t2 = __fmul_rn((float)l, P[l - 1]);
        P[l + 1] = __fdiv_rn(__fsub_rn(t1, t2), (float)(l + 1));
    }
    float* row = &stg[tid * 42];
#pragma unroll
    for (int l = 0; l < NSPH; ++l) {
        float yPl = __fmul_rn(yn[l], P[l]);
        for (int n = 0; n < NRAD; ++n) {
            float z = zf[l * 6 + n];
            float x = __fmul_rn(d, z);
            float s, c;
            glibc_sincosf(x, s, c);
            float j = __fdiv_rn(s, x);
            if (l > 0) {
                float x2 = __fmul_rn(x, x);
                float j1 = __fsub_rn(__fdiv_rn(s, x2), __fdiv_rn(c, x));
                float jm1 = j, jc = j1;
                for (int kk = 1; kk < l; ++kk) {
                    float fk = __fdiv_rn((float)(2 * kk + 1), x);
                    float jn2 = __fsub_rn(__fmul_rn(fk, jc), jm1);
                    jm1 = jc; jc = jn2;
                }
                j = jc;
            }
            float re = __fmul_rn(unc, __fmul_rn(bn[l * 6 + n], j));
            row[l * 6 + n] = __fmul_rn(re, yPl);
        }
    }
    __syncthreads();
    int nv = nT - base; if (nv > BLK) nv = BLK;
    int nf2 = nv * 21;
    const float2* src = (const float2*)stg;
    float2* dst = (float2*)(out + (long long)base * 42);
    for (int i = tid; i < nf2; i += BLK) dst[i] = src[i];
}

extern "C" void kernel_launch(void* const* d_in, const int* in_sizes, int n_in,
                              void* d_out, int out_size, void* d_ws, size_t ws_size,
                              hipStream_t stream) {
    const float* D   = (const float*)d_in[0];
    const float* Ang = (const float*)d_in[1];
    const int*   id3 = (const int*)d_in[2];
    float* out = (float*)d_out;
    int nE = in_sizes[0];
    int nT = in_sizes[1];

    size_t tab_bytes = (size_t)nE * NE_PAD * sizeof(float);
    if (ws_size >= tab_bytes + 512) {
        float* tab = (float*)d_ws;
        float* cst = (float*)((char*)d_ws + tab_bytes);
        setup_k<<<1, 704, 0, stream>>>(cst);
        int gA = (nE + EPB - 1) / EPB;
        edge_k<<<gA, 252, 0, stream>>>(D, cst, tab, nE);
        int gB = (nT + BLK - 1) / BLK;
        trip_k<<<gB, BLK, 0, stream>>>(Ang, id3, tab, cst, out, nT);
    } else {
        float* cst = (float*)d_ws;   // 91 floats
        setup_k<<<1, 704, 0, stream>>>(cst);
        int grid = (nT + BLK - 1) / BLK;
        sph_main<<<grid, BLK, 0, stream>>>(D, Ang, id3, cst, out, nT);
    }
}